// Round 15
// baseline (109.996 us; speedup 1.0000x reference)
//
#include <hip/hip_runtime.h>
#include <hip/hip_bf16.h>

#define B_ROWS 8192
#define C_IN   4096
#define G_GRP  8
#define CG     512
#define J_RANK 512

// ---- GEMM geometry: 128x256 tile, BK=32, 8 waves (2x4), wave tile 64x64 ----
#define BM 128
#define BN 256
#define BK 32
#define NKT (CG / BK)                 // 16 K-tiles

// ---- permute geometry (512-thread variant) ----
#define RPB 8                         // rows per permute block
#define HALF_ROWS 4096
#define HALF_PERM_BLOCKS (HALF_ROWS / RPB)   // 512
#define CONV_BLOCKS 64                // 64 x 8192 float4 = 2M floats

typedef __attribute__((ext_vector_type(8))) short bf16x8;
typedef __attribute__((ext_vector_type(4))) float f32x4;
typedef __attribute__((ext_vector_type(8))) unsigned short u16x8;

struct ushort4v { unsigned short x, y, z, w; };

__device__ __forceinline__ unsigned short f2bf(float f) {
    unsigned int u = __float_as_uint(f);
    unsigned int r = (u + 0x7FFFu + ((u >> 16) & 1u)) >> 16;  // RNE
    return (unsigned short)r;
}

// ---- mega kernel: role by blockIdx ----
// [0, n_gemm): grouped GEMM (mt offset by gemm_mt_base), R9/R12 structure.
// [n_gemm, n_gemm+n_perm): permute rows [perm_row_base + pb*8, +8).
// rest: w fp32->bf16 conversion.
// smem union: gemm A 3x8KB + B 2x16KB = 56KB | permute 3x16KB = 48KB.
// Dispatch plan (phase overlap across the stream):
//   D1: perm(h0) + conv       D2: gemm(h0) || perm(h1)      D3: gemm(h1)
__global__ __launch_bounds__(512, 4) void mega_kernel(
    const float* __restrict__ x, const int* __restrict__ arr,
    unsigned short* __restrict__ xp,
    const float* __restrict__ w, unsigned short* __restrict__ wb,
    const float* __restrict__ bias, float* __restrict__ out,
    int n_gemm, int gemm_mt_base, int n_perm, int perm_row_base) {
    __shared__ __align__(16) unsigned char smem[57344];   // 56 KB union
    const int tid = threadIdx.x;
    const int bid = blockIdx.x;

    if (bid >= n_gemm + n_perm) {
        // ================= w-convert path =================
        const int cb = bid - n_gemm - n_perm;
#pragma unroll
        for (int t = 0; t < 16; ++t) {
            int i = cb * 8192 + t * 512 + tid;
            float4 v = ((const float4*)w)[i];
            ushort4v o;
            o.x = f2bf(v.x); o.y = f2bf(v.y); o.z = f2bf(v.z); o.w = f2bf(v.w);
            ((ushort4v*)wb)[i] = o;
        }
        return;
    }

    if (bid >= n_gemm) {
        // ================= permute path (512 thr, depth-3) =================
        // per-wave VMEM stream per row: 2 stage + 1 store; one barrier/row.
        // vmcnt ladder (in-order sim): r0:2, r1:3, r2..RPB-2:4, last:2.
        float* buf = (float*)smem;   // [3][C_IN]
        const int pb   = bid - n_gemm;
        const int row0 = perm_row_base + pb * RPB;

        const bool is64 = (arr[1] == 0 && arr[3] == 0 && arr[5] == 0 && arr[7] == 0);
        int sidx[8];
#pragma unroll
        for (int k = 0; k < 8; ++k) {
            int p = tid * 8 + k;
            sidx[k] = is64 ? arr[2 * p] : arr[p];
        }

#define PSTAGE(s_, r_)                                                       \
    do {                                                                     \
        const float* src_ = x + (size_t)(row0 + (r_)) * C_IN;                \
        _Pragma("unroll")                                                    \
        for (int i_ = 0; i_ < 2; ++i_) {                                     \
            int c_ = i_ * 2048 + tid * 4;                                    \
            __builtin_amdgcn_global_load_lds(                                \
                (const __attribute__((address_space(1))) unsigned int*)      \
                    (src_ + c_),                                             \
                (__attribute__((address_space(3))) unsigned int*)            \
                    (buf + (s_) * C_IN + c_),                                \
                16, 0, 0);                                                   \
        }                                                                    \
    } while (0)

        PSTAGE(0, 0);
        PSTAGE(1, 1);

#pragma unroll
        for (int r = 0; r < RPB; ++r) {
            if (r == 0)            asm volatile("s_waitcnt vmcnt(2)" ::: "memory");
            else if (r == 1)       asm volatile("s_waitcnt vmcnt(3)" ::: "memory");
            else if (r == RPB - 1) asm volatile("s_waitcnt vmcnt(2)" ::: "memory");
            else                   asm volatile("s_waitcnt vmcnt(4)" ::: "memory");
            __builtin_amdgcn_s_barrier();      // row r staged; row r-1 reads consumed
            __builtin_amdgcn_sched_barrier(0);

            if (r + 2 < RPB) PSTAGE((r + 2) % 3, r + 2);   // slot (r-1)%3 free

            const float* bi = buf + (r % 3) * C_IN;
            u16x8 o;
#pragma unroll
            for (int k = 0; k < 8; ++k) o[k] = f2bf(bi[sidx[k]]);
            *(u16x8*)(xp + (size_t)(row0 + r) * C_IN + tid * 8) = o;
            __builtin_amdgcn_sched_barrier(0);
        }
#undef PSTAGE
        return;
    }

    // ================= gemm path (R9/R12 structure) =================
    unsigned short* ldsA = (unsigned short*)smem;            // 3 x BM*BK
    unsigned short* ldsB = (unsigned short*)(smem + 3 * BM * BK * 2);

    const int g   = bid & 7;
    const int idx = bid >> 3;          // 0..63
    const int mt  = gemm_mt_base + (idx >> 1);
    const int nt  = idx & 1;

    const int l   = tid & 63;
    const int wv  = tid >> 6;          // 0..7
    const int wr  = wv >> 2;           // 0..1
    const int wc  = wv & 3;            // 0..3
    const int lr  = l & 15;
    const int lkq = l >> 4;            // 0..3

    const unsigned short* Ab = xp + (size_t)(mt * BM) * C_IN + g * CG;
    const unsigned short* Bb = wb + (size_t)g * J_RANK * CG + (size_t)(nt * BN) * CG;

    f32x4 acc[4][4];
#pragma unroll
    for (int m = 0; m < 4; ++m)
#pragma unroll
        for (int n = 0; n < 4; ++n) acc[m][n] = (f32x4){0.f, 0.f, 0.f, 0.f};

    const int coff = (lkq ^ ((lr >> 2) & 3)) * 8;

#define STAGE_A(kt_)                                                          \
    do { const int p_ = (kt_) % 3;                                            \
        int c_ = tid;                                                         \
        int rl_ = c_ >> 2, gc_ = (c_ & 3) ^ ((rl_ >> 2) & 3);                 \
        __builtin_amdgcn_global_load_lds(                                     \
            (const __attribute__((address_space(1))) unsigned int*)           \
                (Ab + (size_t)rl_ * C_IN + (kt_) * BK + gc_ * 8),             \
            (__attribute__((address_space(3))) unsigned int*)                 \
                (ldsA + p_ * (BM * BK) + c_ * 8),                             \
            16, 0, 0);                                                        \
    } while (0)

#define STAGE_B(kt_)                                                          \
    do { const int p_ = (kt_) & 1;                                            \
        _Pragma("unroll")                                                     \
        for (int i_ = 0; i_ < 2; ++i_) {                                      \
            int c_ = i_ * 512 + tid;                                          \
            int rl_ = c_ >> 2, gc_ = (c_ & 3) ^ ((rl_ >> 2) & 3);             \
            __builtin_amdgcn_global_load_lds(                                 \
                (const __attribute__((address_space(1))) unsigned int*)       \
                    (Bb + (size_t)rl_ * CG + (kt_) * BK + gc_ * 8),           \
                (__attribute__((address_space(3))) unsigned int*)             \
                    (ldsB + p_ * (BN * BK) + c_ * 8),                         \
                16, 0, 0);                                                    \
        }                                                                     \
    } while (0)

#define LDA(m_) (*(const bf16x8*)&ldsA[bufA * (BM * BK) + (wr * 64 + (m_) * 16 + lr) * BK + coff])
#define LDB(n_) (*(const bf16x8*)&ldsB[bufB * (BN * BK) + (wc * 64 + (n_) * 16 + lr) * BK + coff])

#define PHASE_TAIL()                                                          \
    __builtin_amdgcn_s_barrier();                                             \
    asm volatile("s_waitcnt lgkmcnt(0)" ::: "memory");                        \
    __builtin_amdgcn_sched_barrier(0);                                        \
    __builtin_amdgcn_s_setprio(1)

#define PHASE_END()                                                           \
    __builtin_amdgcn_s_setprio(0);                                            \
    __builtin_amdgcn_s_barrier()

    STAGE_A(0); STAGE_B(0);
    STAGE_A(1); STAGE_B(1);
    asm volatile("s_waitcnt vmcnt(3)" ::: "memory");
    __builtin_amdgcn_s_barrier();

    bf16x8 bfr[4], af[2];

    for (int kt = 0; kt < NKT; ++kt) {
        const int bufA = kt % 3;
        const int bufB = kt & 1;

        // ---- phase 0: read B(all 4) + A(m0,m1); stage A(kt+2) ----
#pragma unroll
        for (int n = 0; n < 4; ++n) bfr[n] = LDB(n);
        af[0] = LDA(0); af[1] = LDA(1);
        if (kt + 2 < NKT) STAGE_A(kt + 2);
        PHASE_TAIL();
#pragma unroll
        for (int mm = 0; mm < 2; ++mm)
#pragma unroll
            for (int n = 0; n < 4; ++n)
                acc[mm][n] = __builtin_amdgcn_mfma_f32_16x16x32_bf16(
                    af[mm], bfr[n], acc[mm][n], 0, 0, 0);
        PHASE_END();

        // ---- phase 1: read A(m2,m3); stage B(kt+2); counted vmcnt ----
        af[0] = LDA(2); af[1] = LDA(3);
        if (kt + 2 < NKT) STAGE_B(kt + 2);
        if (kt <= NKT - 3)      asm volatile("s_waitcnt vmcnt(3)" ::: "memory");
        else if (kt == NKT - 2) asm volatile("s_waitcnt vmcnt(0)" ::: "memory");
        PHASE_TAIL();
#pragma unroll
        for (int mm = 0; mm < 2; ++mm)
#pragma unroll
            for (int n = 0; n < 4; ++n)
                acc[2 + mm][n] = __builtin_amdgcn_mfma_f32_16x16x32_bf16(
                    af[mm], bfr[n], acc[2 + mm][n], 0, 0, 0);
        PHASE_END();
    }
#undef STAGE_A
#undef STAGE_B
#undef LDA
#undef LDB
#undef PHASE_TAIL
#undef PHASE_END

    // epilogue: D frag layout col = lane&15, row = (lane>>4)*4 + r
    const int r0 = mt * BM + wr * 64 + (lkq << 2);
    const int cbase = nt * BN + wc * 64 + lr;
#pragma unroll
    for (int n = 0; n < 4; ++n) {
        int col = cbase + n * 16;
        float bv = bias[g * J_RANK + col];
#pragma unroll
        for (int m = 0; m < 4; ++m) {
            int row = r0 + m * 16;
            float* op = out + (size_t)row * C_IN + g * J_RANK + col;
#pragma unroll
            for (int r = 0; r < 4; ++r)
                op[(size_t)r * C_IN] = acc[m][n][r] + bv;
        }
    }
}

extern "C" void kernel_launch(void* const* d_in, const int* in_sizes, int n_in,
                              void* d_out, int out_size, void* d_ws, size_t ws_size,
                              hipStream_t stream) {
    const float* x    = (const float*)d_in[0];
    const int*   arr  = (const int*)d_in[1];
    const float* w    = (const float*)d_in[2];
    const float* bias = (const float*)d_in[3];
    float* out = (float*)d_out;

    // workspace: xp bf16 [8192][4096] (64MB) | wb bf16 [8][512][512] (4MB)
    unsigned short* xp = (unsigned short*)d_ws;
    unsigned short* wb = xp + (size_t)B_ROWS * C_IN;

    // D1: permute half0 (rows 0..4096) + w-convert
    hipLaunchKernelGGL(mega_kernel, dim3(HALF_PERM_BLOCKS + CONV_BLOCKS), dim3(512),
                       0, stream, x, arr, xp, w, wb, bias, out,
                       0, 0, HALF_PERM_BLOCKS, 0);
    // D2: gemm half0 (mt 0..32) || permute half1 (rows 4096..8192)
    hipLaunchKernelGGL(mega_kernel, dim3(512 + HALF_PERM_BLOCKS), dim3(512),
                       0, stream, x, arr, xp, w, wb, bias, out,
                       512, 0, HALF_PERM_BLOCKS, HALF_ROWS);
    // D3: gemm half1 (mt 32..64)
    hipLaunchKernelGGL(mega_kernel, dim3(512), dim3(512),
                       0, stream, x, arr, xp, w, wb, bias, out,
                       512, 32, 0, 0);
}